// Round 1
// baseline (470.091 us; speedup 1.0000x reference)
//
#include <hip/hip_runtime.h>

// VQ codebook assignment:
//   x:       [B=32, C=256, H=32, W=32] f32
//   embed_w: [K=2048, C=256] f32
// out (flat f32): quantize [B,C,H,W] (8388608) | embed_index [B,H,W] (32768, as float) | loss [1] (=0)

#define CDIM 256
#define KDIM 2048
#define HW   1024
#define NTOK 32768          // B*H*W
#define TN   64             // tokens per block
#define TK   128            // codes per K-tile
#define CB   32             // channel chunk
#define QOFF 8388608        // index region offset in d_out
#define LOFF (QOFF + NTOK)  // loss offset

// ---------------- e_sq = sum_c embed_w[k][c]^2 ----------------
__global__ __launch_bounds__(256) void esq_kernel(const float* __restrict__ ew,
                                                  float* __restrict__ esq,
                                                  float* __restrict__ out) {
    int wave = blockIdx.x * 4 + (threadIdx.x >> 6);   // one wave per codebook row
    int lane = threadIdx.x & 63;
    if (wave < KDIM) {
        const float4 v = *(const float4*)&ew[(size_t)wave * CDIM + lane * 4];
        float s = v.x * v.x + v.y * v.y + v.z * v.z + v.w * v.w;
        #pragma unroll
        for (int m = 32; m >= 1; m >>= 1) s += __shfl_xor(s, m, 64);
        if (lane == 0) esq[wave] = s;
    }
    if (blockIdx.x == 0 && threadIdx.x == 0) out[LOFF] = 0.0f;  // loss = 0
}

// ---------------- fused GEMM + argmin + gather ----------------
__global__ __launch_bounds__(256) void vq_kernel(const float* __restrict__ x,
                                                 const float* __restrict__ ew,
                                                 const float* __restrict__ esq,
                                                 float* __restrict__ out) {
    __shared__ float As[CB][TN];        // channel-major: ds_read_b128 fragments
    __shared__ float Bs[CB][TK + 4];    // +4 pad: keeps 16B align, breaks 32-way write conflict
    __shared__ float redV[TN][17];
    __shared__ int   redI[TN][17];
    __shared__ int   sIdx[TN];

    const int t   = threadIdx.x;
    const int n0  = blockIdx.x * TN;     // first token of this block
    const int b   = n0 >> 10;            // HW = 1024
    const int hw0 = n0 & (HW - 1);
    const int tm  = t & 15;              // token group: tokens tm*4 .. tm*4+3
    const int tn  = t >> 4;              // code group:  codes  tn*8 .. tn*8+7 (per K-tile)

    float bestV[4];
    int   bestI[4];
    #pragma unroll
    for (int i = 0; i < 4; ++i) { bestV[i] = 3.4e38f; bestI[i] = 0; }

    const float* xb = x + (size_t)b * CDIM * HW + hw0;

    for (int kt = 0; kt < KDIM / TK; ++kt) {
        const int k0 = kt * TK;
        float acc[4][8];
        #pragma unroll
        for (int i = 0; i < 4; ++i)
            #pragma unroll
            for (int j = 0; j < 8; ++j) acc[i][j] = 0.0f;

        for (int ct = 0; ct < CDIM / CB; ++ct) {
            const int c0 = ct * CB;
            __syncthreads();   // protect previous tile's readers
            // stage A: 64 tokens x 32 channels (8 scalars/thread, coalesced over hw)
            {
                const int i = t & 63;
                const int cbase = (t >> 6) * 8;
                #pragma unroll
                for (int j = 0; j < 8; ++j) {
                    const int cc = cbase + j;
                    As[cc][i] = xb[(size_t)(c0 + cc) * HW + i];
                }
            }
            // stage B: 128 codes x 32 channels (16 scalars/thread, coalesced over c)
            {
                const int cc = t & 31;
                const int r0 = t >> 5;
                #pragma unroll
                for (int rr = 0; rr < 16; ++rr) {
                    const int row = r0 + rr * 8;
                    Bs[cc][row] = ew[(size_t)(k0 + row) * CDIM + c0 + cc];
                }
            }
            __syncthreads();
            #pragma unroll
            for (int kk = 0; kk < CB; ++kk) {
                float a[4], bv[8];
                *(float4*)a       = *(const float4*)&As[kk][tm * 4];
                *(float4*)&bv[0]  = *(const float4*)&Bs[kk][tn * 8];
                *(float4*)&bv[4]  = *(const float4*)&Bs[kk][tn * 8 + 4];
                #pragma unroll
                for (int i = 0; i < 4; ++i)
                    #pragma unroll
                    for (int j = 0; j < 8; ++j)
                        acc[i][j] = fmaf(a[i], bv[j], acc[i][j]);
            }
        }
        // fold this K-tile into the running best (k visited in increasing order)
        #pragma unroll
        for (int j = 0; j < 8; ++j) {
            const int k = k0 + tn * 8 + j;
            const float e = esq[k];
            #pragma unroll
            for (int i = 0; i < 4; ++i) {
                // e - 2*acc, single rounding — identical to np's e - (2*dot) since 2*dot is exact
                const float d = fmaf(-2.0f, acc[i][j], e);
                if (d < bestV[i]) { bestV[i] = d; bestI[i] = k; }
            }
        }
    }

    // cross-thread argmin merge (lexicographic: value, then lower index)
    #pragma unroll
    for (int i = 0; i < 4; ++i) {
        redV[tm * 4 + i][tn] = bestV[i];
        redI[tm * 4 + i][tn] = bestI[i];
    }
    __syncthreads();
    if (t < TN) {
        float bv = redV[t][0];
        int   bi = redI[t][0];
        #pragma unroll
        for (int s = 1; s < 16; ++s) {
            const float v  = redV[t][s];
            const int   ii = redI[t][s];
            if (v < bv || (v == bv && ii < bi)) { bv = v; bi = ii; }
        }
        sIdx[t] = bi;
        out[QOFF + n0 + t] = (float)bi;   // embed_index as float
    }
    __syncthreads();
    // gather + write quantize: out[b][c][hw0+i] = ew[idx][c]; fixed c -> 64 contiguous hw
    {
        const int i  = t & 63;
        const int cg = t >> 6;
        const int kidx = sIdx[i];
        const float* er = ew + (size_t)kidx * CDIM;
        float* ob = out + (size_t)b * CDIM * HW + hw0 + i;
        #pragma unroll
        for (int p = 0; p < CDIM / 4; ++p) {
            const int c = cg * 64 + p;
            ob[(size_t)c * HW] = er[c];
        }
    }
}

extern "C" void kernel_launch(void* const* d_in, const int* in_sizes, int n_in,
                              void* d_out, int out_size, void* d_ws, size_t ws_size,
                              hipStream_t stream) {
    const float* x  = (const float*)d_in[0];
    const float* ew = (const float*)d_in[1];
    float* out = (float*)d_out;
    float* esq = (float*)d_ws;   // 2048 floats

    esq_kernel<<<KDIM / 4, 256, 0, stream>>>(ew, esq, out);
    vq_kernel<<<NTOK / TN, 256, 0, stream>>>(x, ew, esq, out);
}

// Round 2
// 190.760 us; speedup vs baseline: 2.4643x; 2.4643x over previous
//
#include <hip/hip_runtime.h>

// VQ codebook assignment via split-f16 MFMA GEMM.
//   x:       [B=32, C=256, H=32, W=32] f32   -> tokens [32768][256]
//   embed_w: [K=2048, C=256] f32
// out f32: quantize [32,256,32,32] (8388608) | embed_index [32,32,32] (32768 as float) | loss [1]=0
//
// Math: e' = 8192*e. eh=f16(e'), el=f16((e'-eh)*4096); xh=f16(x), xl=f16((x-xh)*4096).
//   dot' = 8192*dot(x,e) = acc1 + acc2/4096,  acc1=sum xh*eh, acc2=sum (xh*el + xl*eh)
//   d' = 8192*esq - 2*acc1 - 2^-11*acc2 ; argmin_k d' == argmin_k (esq - 2 dot) to ~1e-7 rel.

#define CDIM 256
#define KDIM 2048
#define HW   1024
#define NTOK 32768
#define QOFF 8388608
#define LOFF (QOFF + NTOK)

typedef _Float16 f16x8 __attribute__((ext_vector_type(8)));
typedef _Float16 f16x4 __attribute__((ext_vector_type(4)));
typedef float    f32x4 __attribute__((ext_vector_type(4)));

// ---------------- prep E: limbs + scaled esq + loss ----------------
__global__ __launch_bounds__(256) void prep_e_kernel(const float* __restrict__ ew,
                                                     _Float16* __restrict__ Eh,
                                                     _Float16* __restrict__ El,
                                                     float* __restrict__ esq,
                                                     float* __restrict__ out) {
    const int row  = blockIdx.x * 4 + (threadIdx.x >> 6);
    const int lane = threadIdx.x & 63;
    const float4 v = *(const float4*)&ew[(size_t)row * CDIM + lane * 4];
    float s = v.x * v.x + v.y * v.y + v.z * v.z + v.w * v.w;
    float e0 = v.x * 8192.0f, e1 = v.y * 8192.0f, e2 = v.z * 8192.0f, e3 = v.w * 8192.0f;
    _Float16 h0 = (_Float16)e0, h1 = (_Float16)e1, h2 = (_Float16)e2, h3 = (_Float16)e3;
    f16x4 hv = {h0, h1, h2, h3};
    f16x4 lv = {(_Float16)((e0 - (float)h0) * 4096.0f),
                (_Float16)((e1 - (float)h1) * 4096.0f),
                (_Float16)((e2 - (float)h2) * 4096.0f),
                (_Float16)((e3 - (float)h3) * 4096.0f)};
    *(f16x4*)&Eh[(size_t)row * CDIM + lane * 4] = hv;
    *(f16x4*)&El[(size_t)row * CDIM + lane * 4] = lv;
    #pragma unroll
    for (int m = 32; m >= 1; m >>= 1) s += __shfl_xor(s, m, 64);
    if (lane == 0) esq[row] = s * 8192.0f;
    if (blockIdx.x == 0 && threadIdx.x == 0) out[LOFF] = 0.0f;
}

// ---------------- prep X: transpose [C][HW] -> token-major limb arrays ----------------
__global__ __launch_bounds__(256) void prep_x_kernel(const float* __restrict__ x,
                                                     _Float16* __restrict__ Ah,
                                                     _Float16* __restrict__ Al) {
    __shared__ float tile[32][257];
    const int bid = blockIdx.x;           // 32 b * 8 cblk * 4 hwblk = 1024
    const int b = bid >> 5;
    const int c0 = ((bid >> 2) & 7) * 32;
    const int hw0 = (bid & 3) * 256;
    const int t = threadIdx.x;
    #pragma unroll 8
    for (int r = 0; r < 32; ++r)
        tile[r][t] = x[((size_t)(b * CDIM + c0 + r) << 10) + hw0 + t];
    __syncthreads();
    union { _Float16 h[32]; uint4 q[4]; } Hb, Lb;
    #pragma unroll 8
    for (int r = 0; r < 32; ++r) {
        const float xv = tile[r][t];
        const _Float16 hh = (_Float16)xv;
        Hb.h[r] = hh;
        Lb.h[r] = (_Float16)((xv - (float)hh) * 4096.0f);
    }
    const size_t base = (size_t)(b * HW + hw0 + t) * CDIM + c0;   // f16 units, 16B-aligned
    uint4* dh = (uint4*)(Ah + base);
    uint4* dl = (uint4*)(Al + base);
    #pragma unroll
    for (int j = 0; j < 4; ++j) { dh[j] = Hb.q[j]; dl[j] = Lb.q[j]; }
}

// ---------------- fused MFMA GEMM + argmin ----------------
// 128x128 tile, 4 waves (2x2 of 64x64), BK=64, 16x16x32_f16, XOR slot swizzle.
__global__ __launch_bounds__(256, 2) void vqmm_kernel(const _Float16* __restrict__ Ah,
                                                      const _Float16* __restrict__ Al,
                                                      const _Float16* __restrict__ Eh,
                                                      const _Float16* __restrict__ El,
                                                      const float* __restrict__ esq,
                                                      float* __restrict__ cv,
                                                      int* __restrict__ ci) {
    __shared__ __align__(16) char smem[65536];   // 4 x [128][64] f16 tiles (16KB each)

    const int t = threadIdx.x;
    const int bid = blockIdx.x;
    // XCD-grouped swizzle: the 16 bx-blocks of one by land on one XCD (same id mod 8)
    const int by = (bid & 7) | ((bid >> 7) << 3);   // 0..255
    const int bx = (bid >> 3) & 15;                 // 0..15
    const int tok0 = by << 7;
    const int code0 = bx << 7;
    const int lane = t & 63, wid = t >> 6;
    const int wm = wid >> 1, wn = wid & 1;
    const int g = lane >> 4, lr = lane & 15;

    const f32x4 zf = {0.f, 0.f, 0.f, 0.f};
    f32x4 acc1[4][4], acc2[4][4];
    #pragma unroll
    for (int m = 0; m < 4; ++m)
        #pragma unroll
        for (int n = 0; n < 4; ++n) { acc1[m][n] = zf; acc2[m][n] = zf; }

    // staging geometry: thread t -> (row = t>>3 within 32-row group, phys slot = t&7)
    const int trow = t >> 3;
    const int psl = t & 7;
    const int lsl = psl ^ (trow & 7);               // logical slot stored at psl
    const size_t aoff = (size_t)(tok0 + trow) * CDIM + lsl * 8;   // f16 units
    const size_t boff = (size_t)(code0 + trow) * CDIM + lsl * 8;

    for (int kc = 0; kc < 4; ++kc) {
        __syncthreads();
        const int kof = kc * 64;
        uint4 va[4], vb[4], vc[4], vd[4];
        #pragma unroll
        for (int j = 0; j < 4; ++j) {
            const size_t ro = (size_t)j * 32 * CDIM;
            va[j] = *(const uint4*)(Ah + aoff + ro + kof);
            vb[j] = *(const uint4*)(Al + aoff + ro + kof);
            vc[j] = *(const uint4*)(Eh + boff + ro + kof);
            vd[j] = *(const uint4*)(El + boff + ro + kof);
        }
        #pragma unroll
        for (int j = 0; j < 4; ++j) {
            const int lo = (j * 32 + trow) * 128 + psl * 16;
            *(uint4*)(smem + lo)         = va[j];
            *(uint4*)(smem + 16384 + lo) = vb[j];
            *(uint4*)(smem + 32768 + lo) = vc[j];
            *(uint4*)(smem + 49152 + lo) = vd[j];
        }
        __syncthreads();
        #pragma unroll
        for (int ks = 0; ks < 2; ++ks) {
            const int sl = ((ks * 4 + g) ^ (lr & 7)) * 16;
            f16x8 fa[4], fb[4], fc[4], fd[4];
            #pragma unroll
            for (int m = 0; m < 4; ++m) {
                const int off = (wm * 64 + m * 16 + lr) * 128 + sl;
                fa[m] = *(const f16x8*)(smem + off);
                fb[m] = *(const f16x8*)(smem + 16384 + off);
            }
            #pragma unroll
            for (int n = 0; n < 4; ++n) {
                const int off = (wn * 64 + n * 16 + lr) * 128 + sl;
                fc[n] = *(const f16x8*)(smem + 32768 + off);
                fd[n] = *(const f16x8*)(smem + 49152 + off);
            }
            #pragma unroll
            for (int m = 0; m < 4; ++m)
                #pragma unroll
                for (int n = 0; n < 4; ++n) {
                    acc1[m][n] = __builtin_amdgcn_mfma_f32_16x16x32_f16(fa[m], fc[n], acc1[m][n], 0, 0, 0);
                    acc2[m][n] = __builtin_amdgcn_mfma_f32_16x16x32_f16(fa[m], fd[n], acc2[m][n], 0, 0, 0);
                    acc2[m][n] = __builtin_amdgcn_mfma_f32_16x16x32_f16(fb[m], fc[n], acc2[m][n], 0, 0, 0);
                }
        }
    }
    __syncthreads();
    // epilogue (reuses smem): esq[128] at 0, sv[128][2] at 1024, si[128][2] at 2048
    float* s_esq = (float*)smem;
    float* sv = (float*)(smem + 1024);
    int*   si = (int*)(smem + 2048);
    if (t < 128) s_esq[t] = esq[code0 + t];
    __syncthreads();
    #pragma unroll
    for (int m = 0; m < 4; ++m) {
        #pragma unroll
        for (int r = 0; r < 4; ++r) {
            float bv = 3.4e38f; int bi = 0x7fffffff;
            #pragma unroll
            for (int n = 0; n < 4; ++n) {
                const float d = s_esq[wn * 64 + n * 16 + lr]
                                - 2.0f * acc1[m][n][r]
                                - 4.8828125e-4f * acc2[m][n][r];
                const int cidx = code0 + wn * 64 + n * 16 + lr;
                if (d < bv) { bv = d; bi = cidx; }
            }
            #pragma unroll
            for (int mk = 1; mk < 16; mk <<= 1) {
                const float ov = __shfl_xor(bv, mk, 16);
                const int   oi = __shfl_xor(bi, mk, 16);
                if (ov < bv || (ov == bv && oi < bi)) { bv = ov; bi = oi; }
            }
            if (lr == 0) {
                const int tl = wm * 64 + m * 16 + g * 4 + r;
                sv[tl * 2 + wn] = bv; si[tl * 2 + wn] = bi;
            }
        }
    }
    __syncthreads();
    if (t < 128) {
        const float v0 = sv[t * 2], v1 = sv[t * 2 + 1];
        const int   i0 = si[t * 2], i1 = si[t * 2 + 1];
        const bool swp = (v1 < v0) || (v1 == v0 && i1 < i0);
        const size_t o = (size_t)bx * NTOK + tok0 + t;
        cv[o] = swp ? v1 : v0;
        ci[o] = swp ? i1 : i0;
    }
}

// ---------------- merge 16 candidates + gather quantize ----------------
__global__ __launch_bounds__(256) void merge_gather_kernel(const float* __restrict__ cv,
                                                           const int* __restrict__ ci,
                                                           const float* __restrict__ ew,
                                                           float* __restrict__ out) {
    __shared__ int sIdx[64];
    const int t = threadIdx.x;
    const int n0 = blockIdx.x * 64;
    if (t < 64) {
        const int tok = n0 + t;
        float bv = cv[tok]; int bi = ci[tok];
        #pragma unroll
        for (int s = 1; s < 16; ++s) {
            const float v = cv[(size_t)s * NTOK + tok];
            const int   i2 = ci[(size_t)s * NTOK + tok];
            if (v < bv || (v == bv && i2 < bi)) { bv = v; bi = i2; }
        }
        sIdx[t] = bi;
        out[QOFF + tok] = (float)bi;
    }
    __syncthreads();
    const int b = n0 >> 10, hw0 = n0 & (HW - 1);
    const int i = t & 63, cg = t >> 6;
    const int kidx = sIdx[i];
    const float* er = ew + (size_t)kidx * CDIM;
    float* ob = out + (size_t)b * CDIM * HW + hw0 + i;
    #pragma unroll
    for (int p = 0; p < CDIM / 4; ++p) {
        const int c = cg * 64 + p;
        ob[(size_t)c * HW] = er[c];
    }
}

extern "C" void kernel_launch(void* const* d_in, const int* in_sizes, int n_in,
                              void* d_out, int out_size, void* d_ws, size_t ws_size,
                              hipStream_t stream) {
    const float* x  = (const float*)d_in[0];
    const float* ew = (const float*)d_in[1];
    float* out = (float*)d_out;
    char* ws = (char*)d_ws;

    _Float16* Ah = (_Float16*)(ws);                       // 16,777,216 B
    _Float16* Al = (_Float16*)(ws + 16777216);            // 16,777,216 B
    _Float16* Eh = (_Float16*)(ws + 33554432);            //  1,048,576 B
    _Float16* El = (_Float16*)(ws + 34603008);            //  1,048,576 B
    float*    esq = (float*)(ws + 35651584);              //      8,192 B
    float*    cvv = (float*)(ws + 35659776);              //  2,097,152 B
    int*      cii = (int*)(ws + 37756928);                //  2,097,152 B  (total ~38 MB)

    prep_e_kernel<<<KDIM / 4, 256, 0, stream>>>(ew, Eh, El, esq, out);
    prep_x_kernel<<<1024, 256, 0, stream>>>(x, Ah, Al);
    vqmm_kernel<<<4096, 256, 0, stream>>>(Ah, Al, Eh, El, esq, cvv, cii);
    merge_gather_kernel<<<NTOK / 64, 256, 0, stream>>>(cvv, cii, ew, out);
}